// Round 5
// baseline (593.987 us; speedup 1.0000x reference)
//
#include <hip/hip_runtime.h>
#include <hip/hip_fp16.h>
#include <math.h>

#define HH 32
#define WW 32
#define HWSZ 1024      // H*W
#define CC 384
#define NHEAD 12
#define NGROUP 6
#define HC 32
#define GC 64
#define NS 1024        // n_sample
#define ATTN_SCALE 0.17677669529663687f  // 32^-0.5

// R20 CALIBRATION multipliers — each kernel repeats its (idempotent) work
// N times so its dispatch exceeds the ~43us harness fills and appears in
// rocprof top-5 with full counters. dur/REPS = true per-kernel time.
#define REP_Q    10
#define REP_DWC  10
#define REP_OFF  6
#define REP_KV   8
#define REP_ATTN 4
#define REP_O    10

typedef _Float16 half8_t __attribute__((ext_vector_type(8)));
typedef _Float16 half4_t __attribute__((ext_vector_type(4)));
typedef _Float16 half2_t __attribute__((ext_vector_type(2)));
typedef float    f4_t    __attribute__((ext_vector_type(4)));

// ---------------------------------------------------------------------------
// MFMA GEMM (R15 tiling): Y = W·X + b, 32m x 64n tile, BK=32.
// ---------------------------------------------------------------------------
template<int XLO, int REPS>
__global__ __launch_bounds__(256) void gemm_wx(
    const float* __restrict__ W, const float* __restrict__ bias,
    const float* __restrict__ X, float* __restrict__ Y)
{
    const int bz = blockIdx.z;
    const int tm = blockIdx.y * 32;
    const int tn = blockIdx.x * 64;
    const int tid = threadIdx.x;
    const int w = tid >> 6, lane = tid & 63;
    const int quad = lane >> 4, lcol = lane & 15;

    __shared__ _Float16 sWh[32][40];
    __shared__ _Float16 sXh[64][40];
    __shared__ _Float16 sXl[XLO ? 64 : 1][40];

    const float* Xb = X + (size_t)bz * CC * 1024;
    float* Yb = Y + (size_t)bz * CC * 1024;

#pragma unroll 1
    for (int rep = 0; rep < REPS; ++rep) {
        __syncthreads();
        f4_t acc0 = {0.f, 0.f, 0.f, 0.f}, acc1 = {0.f, 0.f, 0.f, 0.f};

        for (int k0 = 0; k0 < CC; k0 += 32) {
            {
                int m = tid >> 3, k4 = (tid & 7) * 4;
                float4 wv = *(const float4*)&W[(size_t)(tm + m) * CC + k0 + k4];
                half4_t h; h[0] = (_Float16)wv.x; h[1] = (_Float16)wv.y;
                h[2] = (_Float16)wv.z; h[3] = (_Float16)wv.w;
                *(half4_t*)&sWh[m][k4] = h;
            }
            {
                int k = tid >> 3, nj = tid & 7;
                const float* xr = &Xb[(size_t)(k0 + k) * 1024 + tn + nj];
#pragma unroll
                for (int i = 0; i < 8; ++i) {
                    float v = xr[8 * i];
                    _Float16 h = (_Float16)v;
                    sXh[nj + 8 * i][k] = h;
                    if (XLO) sXl[nj + 8 * i][k] = (_Float16)(v - (float)h);
                }
            }
            __syncthreads();

            half8_t Ah0 = *(const half8_t*)&sWh[lcol][quad * 8];
            half8_t Ah1 = *(const half8_t*)&sWh[16 + lcol][quad * 8];
            half8_t Bh  = *(const half8_t*)&sXh[w * 16 + lcol][quad * 8];
            acc0 = __builtin_amdgcn_mfma_f32_16x16x32_f16(Ah0, Bh, acc0, 0, 0, 0);
            acc1 = __builtin_amdgcn_mfma_f32_16x16x32_f16(Ah1, Bh, acc1, 0, 0, 0);
            if (XLO) {
                half8_t Bl = *(const half8_t*)&sXl[w * 16 + lcol][quad * 8];
                acc0 = __builtin_amdgcn_mfma_f32_16x16x32_f16(Ah0, Bl, acc0, 0, 0, 0);
                acc1 = __builtin_amdgcn_mfma_f32_16x16x32_f16(Ah1, Bl, acc1, 0, 0, 0);
            }
            __syncthreads();
        }

#pragma unroll
        for (int r = 0; r < 4; ++r) {
            int m0 = tm + quad * 4 + r;
            Yb[(size_t)m0 * 1024 + tn + w * 16 + lcol]        = acc0[r] + bias[m0];
            Yb[(size_t)(m0 + 16) * 1024 + tn + w * 16 + lcol] = acc1[r] + bias[m0 + 16];
        }
    }
}

// ---------------------------------------------------------------------------
// FUSED MFMA K+V projection (f16 X input).
// ---------------------------------------------------------------------------
__global__ __launch_bounds__(256) void gemm_kv_fused(
    const float* __restrict__ Wk, const float* __restrict__ bk,
    const float* __restrict__ Wv, const float* __restrict__ bv,
    const _Float16* __restrict__ X,
    _Float16* __restrict__ khT, _Float16* __restrict__ vhb)
{
    const int bz = blockIdx.z;
    const int head = blockIdx.y;
    const int tm = head * 32;
    const int tn = blockIdx.x * 64;
    const int tid = threadIdx.x;
    const int w = tid >> 6, lane = tid & 63;
    const int quad = lane >> 4, lcol = lane & 15;
    const int bh = bz * 12 + head;

    __shared__ _Float16 sWk[32][40], sWv[32][40];
    __shared__ _Float16 sXh[64][40];

    const _Float16* Xb = X + (size_t)bz * CC * 1024;

#pragma unroll 1
    for (int rep = 0; rep < REP_KV; ++rep) {
        __syncthreads();
        f4_t ak0 = {0.f, 0.f, 0.f, 0.f}, ak1 = {0.f, 0.f, 0.f, 0.f};
        f4_t av0 = {0.f, 0.f, 0.f, 0.f}, av1 = {0.f, 0.f, 0.f, 0.f};

        for (int k0 = 0; k0 < CC; k0 += 32) {
            {
                int m = tid >> 3, k4 = (tid & 7) * 4;
                float4 wk = *(const float4*)&Wk[(size_t)(tm + m) * CC + k0 + k4];
                float4 wv = *(const float4*)&Wv[(size_t)(tm + m) * CC + k0 + k4];
                half4_t hk; hk[0] = (_Float16)wk.x; hk[1] = (_Float16)wk.y;
                hk[2] = (_Float16)wk.z; hk[3] = (_Float16)wk.w;
                half4_t hv; hv[0] = (_Float16)wv.x; hv[1] = (_Float16)wv.y;
                hv[2] = (_Float16)wv.z; hv[3] = (_Float16)wv.w;
                *(half4_t*)&sWk[m][k4] = hk;
                *(half4_t*)&sWv[m][k4] = hv;
            }
            {
                int k = tid >> 3, nj = (tid & 7) * 8;
                half8_t hv = *(const half8_t*)&Xb[(size_t)(k0 + k) * 1024 + tn + nj];
#pragma unroll
                for (int i = 0; i < 8; ++i)
                    sXh[nj + i][k] = hv[i];
            }
            __syncthreads();

            half8_t Xa = *(const half8_t*)&sXh[w * 16 + lcol][quad * 8];
            half8_t K0 = *(const half8_t*)&sWk[lcol][quad * 8];
            half8_t K1 = *(const half8_t*)&sWk[16 + lcol][quad * 8];
            half8_t V0 = *(const half8_t*)&sWv[lcol][quad * 8];
            half8_t V1 = *(const half8_t*)&sWv[16 + lcol][quad * 8];
            ak0 = __builtin_amdgcn_mfma_f32_16x16x32_f16(Xa, K0, ak0, 0, 0, 0);
            ak1 = __builtin_amdgcn_mfma_f32_16x16x32_f16(Xa, K1, ak1, 0, 0, 0);
            av0 = __builtin_amdgcn_mfma_f32_16x16x32_f16(V0, Xa, av0, 0, 0, 0);
            av1 = __builtin_amdgcn_mfma_f32_16x16x32_f16(V1, Xa, av1, 0, 0, 0);
            __syncthreads();
        }

        {
            float bk0 = bk[tm + lcol], bk1 = bk[tm + 16 + lcol];
#pragma unroll
            for (int r = 0; r < 4; ++r) {
                int n = tn + w * 16 + quad * 4 + r;
                khT[((size_t)bh * 1024 + n) * 32 + lcol]      = (_Float16)(ak0[r] + bk0);
                khT[((size_t)bh * 1024 + n) * 32 + 16 + lcol] = (_Float16)(ak1[r] + bk1);
            }
        }
        {
#pragma unroll
            for (int r = 0; r < 4; ++r) {
                int hc0 = quad * 4 + r;
                vhb[((size_t)bh * 32 + hc0) * 1024 + tn + w * 16 + lcol] =
                    (_Float16)(av0[r] + bv[tm + hc0]);
                vhb[((size_t)bh * 32 + hc0 + 16) * 1024 + tn + w * 16 + lcol] =
                    (_Float16)(av1[r] + bv[tm + hc0 + 16]);
            }
        }
    }
}

// ---------------------------------------------------------------------------
// Depthwise 7x7 conv, zero pad 3.
// ---------------------------------------------------------------------------
__global__ __launch_bounds__(256) void dwconv_kernel(
    const float* __restrict__ q, const float* __restrict__ dww,
    const float* __restrict__ dwb, float* __restrict__ oconv)
{
    const int bc = blockIdx.x;
    const int bg = bc >> 6, c = bc & 63;
    const int b = bg / 6, g = bg % 6;
    const float* plane = q + ((size_t)b * CC + g * 64 + c) * 1024;

    __shared__ float sp[1024];
    __shared__ float sw[49];
    const int tid = threadIdx.x;

#pragma unroll 1
    for (int rep = 0; rep < REP_DWC; ++rep) {
        __syncthreads();
        for (int i = tid; i < 1024; i += 256) sp[i] = plane[i];
        if (tid < 49) sw[tid] = dww[c * 49 + tid];
        __syncthreads();

        const float bias = dwb[c];
        for (int i = tid; i < 1024; i += 256) {
            int y = i >> 5, x = i & 31;
            float s = 0.f;
#pragma unroll
            for (int ky = 0; ky < 7; ++ky) {
                int yy = y + ky - 3;
                if (yy < 0 || yy > 31) continue;
#pragma unroll
                for (int kx = 0; kx < 7; ++kx) {
                    int xx = x + kx - 3;
                    if (xx < 0 || xx > 31) continue;
                    s += sp[yy * 32 + xx] * sw[ky * 7 + kx];
                }
            }
            oconv[(size_t)bc * 1024 + i] = s + bias;
        }
    }
}

// ---------------------------------------------------------------------------
// LN + GELU + pw + tanh ONCE per pixel -> pos, then gather all 64 ch -> xs.
// ---------------------------------------------------------------------------
__global__ __launch_bounds__(256) void offset_sample_once_kernel(
    const float* __restrict__ oconv, const float* __restrict__ lng,
    const float* __restrict__ lnb, const float* __restrict__ pw,
    const float* __restrict__ x, float* __restrict__ pos,
    _Float16* __restrict__ xs)
{
    const int bg = blockIdx.y;
    const int px0 = blockIdx.x * 64;
    const int t = threadIdx.x;
    const int cg = t >> 6, pl = t & 63;
    const int px = px0 + pl;
    const int b = bg / 6, g = bg % 6;

    __shared__ float red[4][64];
    __shared__ float spos[64][2];

#pragma unroll 1
    for (int rep = 0; rep < REP_OFF; ++rep) {
        __syncthreads();
        const float* base = oconv + ((size_t)bg * 64 + cg * 16) * 1024 + px;
        float col[16];
        float s = 0.f;
#pragma unroll
        for (int i = 0; i < 16; ++i) { col[i] = base[(size_t)i * 1024]; s += col[i]; }
        red[cg][pl] = s;
        __syncthreads();
        float mu = (red[0][pl] + red[1][pl] + red[2][pl] + red[3][pl]) * (1.f / 64.f);
        float v = 0.f;
#pragma unroll
        for (int i = 0; i < 16; ++i) { float d = col[i] - mu; v += d * d; }
        __syncthreads();
        red[cg][pl] = v;
        __syncthreads();
        float inv = rsqrtf((red[0][pl] + red[1][pl] + red[2][pl] + red[3][pl]) * (1.f / 64.f) + 1e-5f);

        float oy = 0.f, ox = 0.f;
#pragma unroll
        for (int i = 0; i < 16; ++i) {
            int c = cg * 16 + i;
            float val = (col[i] - mu) * inv * lng[c] + lnb[c];
            float gl = 0.5f * val * (1.f + erff(val * 0.70710678118654752440f));
            oy += gl * pw[c];
            ox += gl * pw[64 + c];
        }
        __syncthreads();
        red[cg][pl] = oy;
        __syncthreads();
        float oyt = red[0][pl] + red[1][pl] + red[2][pl] + red[3][pl];
        __syncthreads();
        red[cg][pl] = ox;
        __syncthreads();
        if (cg == 0) {
            float oxt = red[0][pl] + red[1][pl] + red[2][pl] + red[3][pl];
            float offy = tanhf(oyt) * (2.0f / 32.0f);
            float offx = tanhf(oxt) * (2.0f / 32.0f);
            int y = px >> 5, xx = px & 31;
            float ry = ((y + 0.5f) / 32.f) * 2.f - 1.f;
            float rx = ((xx + 0.5f) / 32.f) * 2.f - 1.f;
            float pyv = offy + ry, pxv = offx + rx;
            spos[pl][0] = pyv; spos[pl][1] = pxv;
            pos[((size_t)bg * 1024 + px) * 2 + 0] = pyv;
            pos[((size_t)bg * 1024 + px) * 2 + 1] = pxv;
        }
        __syncthreads();

        float py = spos[pl][0], pxv = spos[pl][1];
        float gx = (pxv + 1.f) * 0.5f * 31.f;
        float gy = (py + 1.f) * 0.5f * 31.f;
        float x0f = floorf(gx), y0f = floorf(gy);
        float wx = gx - x0f, wy = gy - y0f;
        int x0 = (int)x0f, y0 = (int)y0f;
        float vx0 = ((unsigned)x0 <= 31u) ? 1.f : 0.f;
        float vx1 = ((unsigned)(x0 + 1) <= 31u) ? 1.f : 0.f;
        float vy0 = ((unsigned)y0 <= 31u) ? 1.f : 0.f;
        float vy1 = ((unsigned)(y0 + 1) <= 31u) ? 1.f : 0.f;
        float w00 = (1.f - wx) * (1.f - wy) * vx0 * vy0;
        float w01 = wx * (1.f - wy) * vx1 * vy0;
        float w10 = (1.f - wx) * wy * vx0 * vy1;
        float w11 = wx * wy * vx1 * vy1;
        int xc0 = min(max(x0, 0), 31), xc1 = min(max(x0 + 1, 0), 31);
        int yc0 = min(max(y0, 0), 31), yc1 = min(max(y0 + 1, 0), 31);
        int i00 = yc0 * 32 + xc0, i01 = yc0 * 32 + xc1;
        int i10 = yc1 * 32 + xc0, i11 = yc1 * 32 + xc1;

        const float* xg = x + ((size_t)b * CC + g * 64) * 1024;
        _Float16* xso = xs + ((size_t)b * CC + g * 64) * 1024 + px;
#pragma unroll
        for (int cs = 0; cs < 4; ++cs) {
            int c0 = cs * 16 + cg * 4;
#pragma unroll
            for (int i = 0; i < 4; ++i) {
                const float* plane = xg + (size_t)(c0 + i) * 1024;
                xso[(size_t)(c0 + i) * 1024] =
                    (_Float16)(plane[i00] * w00 + plane[i01] * w01
                             + plane[i10] * w10 + plane[i11] * w11);
            }
        }
    }
}

// ---------------------------------------------------------------------------
// MFMA flash attention, TWO HEADS PER BLOCK.
// ---------------------------------------------------------------------------
__global__ __launch_bounds__(256) void attn_mfma_kernel(
    const float* __restrict__ q, const _Float16* __restrict__ khT,
    const _Float16* __restrict__ vhb, const float* __restrict__ pos,
    const float* __restrict__ rpe, float* __restrict__ out)
{
    const int bgp = blockIdx.y;            // 0..11 = (b, g)
    const int b = bgp / 6, g = bgp % 6;
    const int h0 = g * 2;
    const int bh0 = b * 12 + h0, bh1 = bh0 + 1;
    const int mblk = blockIdx.x * 16;
    const int tid = threadIdx.x;
    const int w = tid >> 6, lane = tid & 63;
    const int quad = lane >> 4, lcol = lane & 15;

    __shared__ __align__(16) char smem[50944];
    half2_t*  srpeA = (half2_t*)smem;
    half2_t*  srpeB = (half2_t*)(smem + 8832);
    _Float16* sqh   = (_Float16*)(smem + 17664);
    _Float16* spw   = (_Float16*)(smem + 19712) + w * 2304;   // h0: +0, h1: +1152
    float*    cml0  = (float*)(smem + 38144);
    float*    cml1  = (float*)(smem + 38400);
    float2*   skxy  = (float2*)(smem + 38656);
    int*      siy   = (int*)(smem + 46848);
    float*    comb0 = (float*)(smem + 19712);
    float*    comb1 = (float*)(smem + 19712 + 9216);

    const float qyw = (((mblk >> 5) + 0.5f) * (1.f / 32.f)) * 2.f - 1.f;
    int r0; {
        float gy_lo = (qyw - 1.03125f) * 15.5f + 31.f;
        r0 = (int)floorf(gy_lo);
        r0 = min(max(r0, 0), 28);
    }

#pragma unroll 1
    for (int rep = 0; rep < REP_ATTN; ++rep) {
        __syncthreads();
        {
            const float* rp0 = rpe + (size_t)h0 * 3969;
            const float* rp1 = rp0 + 3969;
            for (int i = tid; i < 35 * 63; i += 256) {
                int y = i / 63, xx = i - y * 63;
                int gi = (r0 + y) * 63 + xx;
                float a0 = rp0[gi], b0 = (xx < 62) ? rp0[gi + 1] : 0.f;
                float a1 = rp1[gi], b1 = (xx < 62) ? rp1[gi + 1] : 0.f;
                half2_t hA; hA[0] = (_Float16)a0; hA[1] = (_Float16)a1;
                half2_t hB; hB[0] = (_Float16)b0; hB[1] = (_Float16)b1;
                srpeA[i] = hA;
                srpeB[i] = hB;
            }
        }
        {
            const float* qb = q + ((size_t)b * CC + h0 * 32) * 1024 + mblk;
            for (int i = tid; i < 1024; i += 256) {
                int hh = i >> 9, rem = i & 511;
                int hc = rem >> 4, m = rem & 15;
                sqh[hh * 512 + m * 32 + hc] =
                    (_Float16)qb[(size_t)(hh * 32 + hc) * 1024 + m];
            }
        }
        {
            const float2* pgv = (const float2*)(pos + (size_t)bgp * 2048);
            for (int i = tid; i < 1024; i += 256) {
                float2 pp = pgv[i];
                float gy = (qyw - pp.x) * 15.5f + 31.f;
                float y0f = floorf(gy);
                skxy[i] = make_float2(pp.y, gy - y0f);
                siy[i] = ((int)y0f - r0) * 63;
            }
        }
        __syncthreads();

        half8_t qf0 = *(const half8_t*)&sqh[lcol * 32 + quad * 8];
        half8_t qf1 = *(const half8_t*)&sqh[512 + lcol * 32 + quad * 8];
        const float qx = (((mblk & 31) + lcol + 0.5f) * (1.f / 32.f)) * 2.f - 1.f;

        const _Float16* khb0 = khT + (size_t)bh0 * 1024 * 32;
        const _Float16* khb1 = khT + (size_t)bh1 * 1024 * 32;
        const _Float16* vhh0 = vhb + (size_t)bh0 * 32 * 1024;
        const _Float16* vhh1 = vhb + (size_t)bh1 * 32 * 1024;

        f4_t o00 = {0.f, 0.f, 0.f, 0.f}, o01 = {0.f, 0.f, 0.f, 0.f};
        f4_t o10 = {0.f, 0.f, 0.f, 0.f}, o11 = {0.f, 0.f, 0.f, 0.f};
        float lsum0 = 0.f, lsum1 = 0.f;

#pragma unroll 1
        for (int c = 0; c < 4; ++c) {
            const int n0 = w * 256 + c * 64;

            half8_t khv0[4], khv1[4];
#pragma unroll
            for (int t = 0; t < 4; ++t) {
                size_t off = (size_t)(n0 + t * 16 + lcol) * 32 + quad * 8;
                khv0[t] = *(const half8_t*)&khb0[off];
                khv1[t] = *(const half8_t*)&khb1[off];
            }

            f4_t S0[4], S1[4];
#pragma unroll
            for (int t = 0; t < 4; ++t) {
                f4_t s0 = {0.f, 0.f, 0.f, 0.f}, s1 = {0.f, 0.f, 0.f, 0.f};
                s0 = __builtin_amdgcn_mfma_f32_16x16x32_f16(khv0[t], qf0, s0, 0, 0, 0);
                s1 = __builtin_amdgcn_mfma_f32_16x16x32_f16(khv1[t], qf1, s1, 0, 0, 0);
#pragma unroll
                for (int r = 0; r < 4; ++r) {
                    int key = n0 + t * 16 + quad * 4 + r;
                    float2 kxy = skxy[key];
                    int iy = siy[key];
                    float gx = (qx - kxy.x) * 15.5f + 31.f;
                    float x0f = floorf(gx);
                    float wxf = gx - x0f;
                    int i00 = iy + (int)x0f;
                    half2_t a0 = srpeA[i00];
                    half2_t b0 = srpeB[i00];
                    half2_t a1 = srpeA[i00 + 63];
                    half2_t b1 = srpeB[i00 + 63];
                    _Float16 wxs = (_Float16)wxf;
                    _Float16 wys = (_Float16)kxy.y;
                    half2_t wxh; wxh[0] = wxs; wxh[1] = wxs;
                    half2_t wyh; wyh[0] = wys; wyh[1] = wys;
                    half2_t top = a0 + (b0 - a0) * wxh;
                    half2_t bot = a1 + (b1 - a1) * wxh;
                    half2_t res = top + (bot - top) * wyh;
                    s0[r] = s0[r] * ATTN_SCALE + (float)res[0];
                    s1[r] = s1[r] * ATTN_SCALE + (float)res[1];
                }
                S0[t] = s0; S1[t] = s1;
            }

            half8_t vv00[2], vv01[2];
#pragma unroll
            for (int kp = 0; kp < 2; ++kp) {
                int nb = n0 + kp * 32 + quad * 8;
                vv00[kp] = *(const half8_t*)&vhh0[(size_t)lcol * 1024 + nb];
                vv01[kp] = *(const half8_t*)&vhh0[(size_t)(16 + lcol) * 1024 + nb];
            }

#pragma unroll
            for (int t = 0; t < 4; ++t) {
                float p0 = __expf(S0[t][0]), p1 = __expf(S0[t][1]);
                float p2 = __expf(S0[t][2]), p3 = __expf(S0[t][3]);
                lsum0 += (p0 + p1) + (p2 + p3);
                half4_t h;
                h[0] = (_Float16)p0; h[1] = (_Float16)p1;
                h[2] = (_Float16)p2; h[3] = (_Float16)p3;
                *(half4_t*)&spw[lcol * 72 + t * 16 + quad * 4] = h;
                float r0e = __expf(S1[t][0]), r1e = __expf(S1[t][1]);
                float r2e = __expf(S1[t][2]), r3e = __expf(S1[t][3]);
                lsum1 += (r0e + r1e) + (r2e + r3e);
                half4_t h1;
                h1[0] = (_Float16)r0e; h1[1] = (_Float16)r1e;
                h1[2] = (_Float16)r2e; h1[3] = (_Float16)r3e;
                *(half4_t*)&spw[1152 + lcol * 72 + t * 16 + quad * 4] = h1;
            }

#pragma unroll
            for (int kp = 0; kp < 2; ++kp) {
                half8_t pb = *(const half8_t*)&spw[lcol * 72 + kp * 32 + quad * 8];
                o00 = __builtin_amdgcn_mfma_f32_16x16x32_f16(vv00[kp], pb, o00, 0, 0, 0);
                o01 = __builtin_amdgcn_mfma_f32_16x16x32_f16(vv01[kp], pb, o01, 0, 0, 0);
            }
#pragma unroll
            for (int kp = 0; kp < 2; ++kp) {
                int nb = n0 + kp * 32 + quad * 8;
                half8_t v0 = *(const half8_t*)&vhh1[(size_t)lcol * 1024 + nb];
                half8_t v1 = *(const half8_t*)&vhh1[(size_t)(16 + lcol) * 1024 + nb];
                half8_t pb = *(const half8_t*)&spw[1152 + lcol * 72 + kp * 32 + quad * 8];
                o10 = __builtin_amdgcn_mfma_f32_16x16x32_f16(v0, pb, o10, 0, 0, 0);
                o11 = __builtin_amdgcn_mfma_f32_16x16x32_f16(v1, pb, o11, 0, 0, 0);
            }
        }

        lsum0 += __shfl_xor(lsum0, 16); lsum0 += __shfl_xor(lsum0, 32);
        lsum1 += __shfl_xor(lsum1, 16); lsum1 += __shfl_xor(lsum1, 32);

        __syncthreads();

        *(f4_t*)&comb0[(w * 16 + lcol) * 36 + quad * 4]      = o00;
        *(f4_t*)&comb0[(w * 16 + lcol) * 36 + 16 + quad * 4] = o01;
        *(f4_t*)&comb1[(w * 16 + lcol) * 36 + quad * 4]      = o10;
        *(f4_t*)&comb1[(w * 16 + lcol) * 36 + 16 + quad * 4] = o11;
        if (quad == 0) {
            cml0[w * 16 + lcol] = lsum0;
            cml1[w * 16 + lcol] = lsum1;
        }
        __syncthreads();

#pragma unroll
        for (int i = 0; i < 2; ++i) {
            int idx = tid + i * 256;
            int qq = idx >> 5, hc = idx & 31;
            {
                float L = cml0[qq] + cml0[16 + qq] + cml0[32 + qq] + cml0[48 + qq];
                float o = comb0[(0 * 16 + qq) * 36 + hc]
                        + comb0[(1 * 16 + qq) * 36 + hc]
                        + comb0[(2 * 16 + qq) * 36 + hc]
                        + comb0[(3 * 16 + qq) * 36 + hc];
                out[((size_t)b * CC + h0 * 32 + hc) * 1024 + mblk + qq] = o / L;
            }
            {
                float L = cml1[qq] + cml1[16 + qq] + cml1[32 + qq] + cml1[48 + qq];
                float o = comb1[(0 * 16 + qq) * 36 + hc]
                        + comb1[(1 * 16 + qq) * 36 + hc]
                        + comb1[(2 * 16 + qq) * 36 + hc]
                        + comb1[(3 * 16 + qq) * 36 + hc];
                out[((size_t)b * CC + (h0 + 1) * 32 + hc) * 1024 + mblk + qq] = o / L;
            }
        }
    }
}

// ---------------------------------------------------------------------------
extern "C" void kernel_launch(void* const* d_in, const int* in_sizes, int n_in,
                              void* d_out, int out_size, void* d_ws, size_t ws_size,
                              hipStream_t stream) {
    const float* x   = (const float*)d_in[0];
    const float* Wq  = (const float*)d_in[1];
    const float* bq  = (const float*)d_in[2];
    const float* Wk  = (const float*)d_in[3];
    const float* bk  = (const float*)d_in[4];
    const float* Wv  = (const float*)d_in[5];
    const float* bv  = (const float*)d_in[6];
    const float* Wo  = (const float*)d_in[7];
    const float* bo  = (const float*)d_in[8];
    const float* dww = (const float*)d_in[9];
    const float* dwb = (const float*)d_in[10];
    const float* lng = (const float*)d_in[11];
    const float* lnb = (const float*)d_in[12];
    const float* pw  = (const float*)d_in[13];
    const float* rpe = (const float*)d_in[14];

    float* ws = (float*)d_ws;
    const size_t SZ = 786432;           // 2*384*1024 floats
    float* qbuf  = ws;
    _Float16* xs = (_Float16*)(ws + 1 * SZ);     // f16
    float* abuf  = ws + 2 * SZ;
    float* oconv = ws + 3 * SZ;
    _Float16* khT = (_Float16*)(ws + 4 * SZ);
    _Float16* vhb = (_Float16*)(ws + 5 * SZ);
    float* pos   = ws + 6 * SZ;

    dim3 gqo(16, 12, 2);
    gemm_wx<0, REP_Q><<<gqo, 256, 0, stream>>>(Wq, bq, x, qbuf);
    dwconv_kernel<<<768, 256, 0, stream>>>(qbuf, dww, dwb, oconv);
    offset_sample_once_kernel<<<dim3(16, 12), 256, 0, stream>>>(
        oconv, lng, lnb, pw, x, pos, xs);
    gemm_kv_fused<<<dim3(16, 12, 2), 256, 0, stream>>>(Wk, bk, Wv, bv, xs, khT, vhb);
    attn_mfma_kernel<<<dim3(64, 12), 256, 0, stream>>>(qbuf, khT, vhb, pos, rpe, abuf);
    gemm_wx<1, REP_O><<<gqo, 256, 0, stream>>>(Wo, bo, abuf, (float*)d_out);
}

// Round 6
// 158.352 us; speedup vs baseline: 3.7511x; 3.7511x over previous
//
#include <hip/hip_runtime.h>
#include <hip/hip_fp16.h>
#include <math.h>

#define HH 32
#define WW 32
#define HWSZ 1024      // H*W
#define CC 384
#define NHEAD 12
#define NGROUP 6
#define HC 32
#define GC 64
#define NS 1024        // n_sample
#define ATTN_SCALE 0.17677669529663687f  // 32^-0.5

typedef _Float16 half8_t __attribute__((ext_vector_type(8)));
typedef _Float16 half4_t __attribute__((ext_vector_type(4)));
typedef _Float16 half2_t __attribute__((ext_vector_type(2)));
typedef float    f4_t    __attribute__((ext_vector_type(4)));

// ---------------------------------------------------------------------------
// R21 MFMA GEMM: Y = W·X + b. 32m x 32n tile, BK=32, grid (32,12,2)=768
// blocks -> 3 blocks/CU (R20 calibration showed the 64n version was
// grid-limited at 1.5 blocks/CU, Occupancy 16%, MfmaUtil 3.6%).
// One 16x16 output quadrant per wave; register prefetch of next K-tile
// issued between barriers hides global latency under ds_read+MFMA.
// W pure f16; X pure f16 (XLO=0, q-proj) or f16 hi/lo (XLO=1, o-proj).
// ---------------------------------------------------------------------------
template<int XLO>
__global__ __launch_bounds__(256) void gemm_wx(
    const float* __restrict__ W, const float* __restrict__ bias,
    const float* __restrict__ X, float* __restrict__ Y)
{
    const int bz = blockIdx.z;
    const int tm = blockIdx.y * 32;
    const int tn = blockIdx.x * 32;
    const int tid = threadIdx.x;
    const int w = tid >> 6, lane = tid & 63;
    const int quad = lane >> 4, lcol = lane & 15;
    const int wr = w >> 1, wc = w & 1;       // wave's output quadrant

    __shared__ _Float16 sW[32][40];          // [m][k], 80B rows: 16B-aligned
    __shared__ _Float16 sX[32][40];          // [n][k]
    __shared__ _Float16 sXl[XLO ? 32 : 1][40];

    const float* Xb = X + (size_t)bz * CC * 1024;
    float* Yb = Y + (size_t)bz * CC * 1024;

    const int m  = tid >> 3;                 // 0..31 (also X row-in-tile)
    const int j4 = (tid & 7) * 4;            // 0..28 (also W k-offset)

    // prefetch K-tile 0
    float4 wv = *(const float4*)&W[(size_t)(tm + m) * CC + j4];
    float4 xv = *(const float4*)&Xb[(size_t)m * 1024 + tn + j4];

    f4_t acc = {0.f, 0.f, 0.f, 0.f};

#pragma unroll 1
    for (int k0 = 0; k0 < CC; k0 += 32) {
        {   // write staged regs -> LDS
            half4_t hw; hw[0] = (_Float16)wv.x; hw[1] = (_Float16)wv.y;
            hw[2] = (_Float16)wv.z; hw[3] = (_Float16)wv.w;
            *(half4_t*)&sW[m][j4] = hw;
#pragma unroll
            for (int i = 0; i < 4; ++i) {
                float v = (i == 0) ? xv.x : (i == 1) ? xv.y : (i == 2) ? xv.z : xv.w;
                _Float16 h = (_Float16)v;
                sX[j4 + i][m] = h;
                if (XLO) sXl[j4 + i][m] = (_Float16)(v - (float)h);
            }
        }
        __syncthreads();

        // issue next tile's loads (overlap ds_read+MFMA+barrier)
        if (k0 + 32 < CC) {
            wv = *(const float4*)&W[(size_t)(tm + m) * CC + k0 + 32 + j4];
            xv = *(const float4*)&Xb[(size_t)(k0 + 32 + m) * 1024 + tn + j4];
        }

        half8_t A = *(const half8_t*)&sW[wr * 16 + lcol][quad * 8];
        half8_t B = *(const half8_t*)&sX[wc * 16 + lcol][quad * 8];
        acc = __builtin_amdgcn_mfma_f32_16x16x32_f16(A, B, acc, 0, 0, 0);
        if (XLO) {
            half8_t Bl = *(const half8_t*)&sXl[wc * 16 + lcol][quad * 8];
            acc = __builtin_amdgcn_mfma_f32_16x16x32_f16(A, Bl, acc, 0, 0, 0);
        }
        __syncthreads();
    }

#pragma unroll
    for (int r = 0; r < 4; ++r) {
        int m0 = tm + wr * 16 + quad * 4 + r;
        Yb[(size_t)m0 * 1024 + tn + wc * 16 + lcol] = acc[r] + bias[m0];
    }
}

// ---------------------------------------------------------------------------
// R21 FUSED MFMA K+V projection, 32n tiles, grid (32,12,2)=768 blocks.
// Waves 0,1 compute K quadrants; waves 2,3 compute V quadrants (2 MFMA
// per wave per K-step). X f16 input; register prefetch as in gemm_wx.
//   K: D[n][hc] = X^T·Wk^T -> khT [bh][n][hc]
//   V: D[hc][n] = Wv·X     -> vhb [bh][hc][n]
// ---------------------------------------------------------------------------
__global__ __launch_bounds__(256) void gemm_kv_fused(
    const float* __restrict__ Wk, const float* __restrict__ bk,
    const float* __restrict__ Wv, const float* __restrict__ bv,
    const _Float16* __restrict__ X,
    _Float16* __restrict__ khT, _Float16* __restrict__ vhb)
{
    const int bz = blockIdx.z;
    const int head = blockIdx.y;
    const int tm = head * 32;
    const int tn = blockIdx.x * 32;
    const int tid = threadIdx.x;
    const int w = tid >> 6, lane = tid & 63;
    const int quad = lane >> 4, lcol = lane & 15;
    const int bh = bz * 12 + head;
    const int nt = w & 1;                    // n sub-tile for this wave

    __shared__ _Float16 sWk[32][40], sWv[32][40];
    __shared__ _Float16 sX[32][40];          // [n][k]

    const _Float16* Xb = X + (size_t)bz * CC * 1024;

    const int m  = tid >> 3;
    const int j4 = (tid & 7) * 4;

    float4 wkv = *(const float4*)&Wk[(size_t)(tm + m) * CC + j4];
    float4 wvv = *(const float4*)&Wv[(size_t)(tm + m) * CC + j4];
    half4_t xh = *(const half4_t*)&Xb[(size_t)m * 1024 + tn + j4];

    f4_t a0 = {0.f, 0.f, 0.f, 0.f}, a1 = {0.f, 0.f, 0.f, 0.f};

#pragma unroll 1
    for (int k0 = 0; k0 < CC; k0 += 32) {
        {
            half4_t hk; hk[0] = (_Float16)wkv.x; hk[1] = (_Float16)wkv.y;
            hk[2] = (_Float16)wkv.z; hk[3] = (_Float16)wkv.w;
            half4_t hv; hv[0] = (_Float16)wvv.x; hv[1] = (_Float16)wvv.y;
            hv[2] = (_Float16)wvv.z; hv[3] = (_Float16)wvv.w;
            *(half4_t*)&sWk[m][j4] = hk;
            *(half4_t*)&sWv[m][j4] = hv;
#pragma unroll
            for (int i = 0; i < 4; ++i)
                sX[j4 + i][m] = xh[i];
        }
        __syncthreads();

        if (k0 + 32 < CC) {
            wkv = *(const float4*)&Wk[(size_t)(tm + m) * CC + k0 + 32 + j4];
            wvv = *(const float4*)&Wv[(size_t)(tm + m) * CC + k0 + 32 + j4];
            xh  = *(const half4_t*)&Xb[(size_t)(k0 + 32 + m) * 1024 + tn + j4];
        }

        half8_t Xa = *(const half8_t*)&sX[nt * 16 + lcol][quad * 8];
        if (w < 2) {   // K: A = X (n rows), B = Wk (hc cols)
            half8_t K0 = *(const half8_t*)&sWk[lcol][quad * 8];
            half8_t K1 = *(const half8_t*)&sWk[16 + lcol][quad * 8];
            a0 = __builtin_amdgcn_mfma_f32_16x16x32_f16(Xa, K0, a0, 0, 0, 0);
            a1 = __builtin_amdgcn_mfma_f32_16x16x32_f16(Xa, K1, a1, 0, 0, 0);
        } else {       // V: A = Wv (hc rows), B = X (n cols)
            half8_t V0 = *(const half8_t*)&sWv[lcol][quad * 8];
            half8_t V1 = *(const half8_t*)&sWv[16 + lcol][quad * 8];
            a0 = __builtin_amdgcn_mfma_f32_16x16x32_f16(V0, Xa, a0, 0, 0, 0);
            a1 = __builtin_amdgcn_mfma_f32_16x16x32_f16(V1, Xa, a1, 0, 0, 0);
        }
        __syncthreads();
    }

    if (w < 2) {
        float bk0 = bk[tm + lcol], bk1 = bk[tm + 16 + lcol];
#pragma unroll
        for (int r = 0; r < 4; ++r) {
            int n = tn + nt * 16 + quad * 4 + r;
            khT[((size_t)bh * 1024 + n) * 32 + lcol]      = (_Float16)(a0[r] + bk0);
            khT[((size_t)bh * 1024 + n) * 32 + 16 + lcol] = (_Float16)(a1[r] + bk1);
        }
    } else {
#pragma unroll
        for (int r = 0; r < 4; ++r) {
            int hc0 = quad * 4 + r;
            vhb[((size_t)bh * 32 + hc0) * 1024 + tn + nt * 16 + lcol] =
                (_Float16)(a0[r] + bv[tm + hc0]);
            vhb[((size_t)bh * 32 + hc0 + 16) * 1024 + tn + nt * 16 + lcol] =
                (_Float16)(a1[r] + bv[tm + hc0 + 16]);
        }
    }
}

// ---------------------------------------------------------------------------
// Depthwise 7x7 conv, zero pad 3 (unchanged).
// ---------------------------------------------------------------------------
__global__ __launch_bounds__(256) void dwconv_kernel(
    const float* __restrict__ q, const float* __restrict__ dww,
    const float* __restrict__ dwb, float* __restrict__ oconv)
{
    const int bc = blockIdx.x;
    const int bg = bc >> 6, c = bc & 63;
    const int b = bg / 6, g = bg % 6;
    const float* plane = q + ((size_t)b * CC + g * 64 + c) * 1024;

    __shared__ float sp[1024];
    __shared__ float sw[49];
    const int tid = threadIdx.x;
    for (int i = tid; i < 1024; i += 256) sp[i] = plane[i];
    if (tid < 49) sw[tid] = dww[c * 49 + tid];
    __syncthreads();

    const float bias = dwb[c];
    for (int i = tid; i < 1024; i += 256) {
        int y = i >> 5, x = i & 31;
        float s = 0.f;
#pragma unroll
        for (int ky = 0; ky < 7; ++ky) {
            int yy = y + ky - 3;
            if (yy < 0 || yy > 31) continue;
#pragma unroll
            for (int kx = 0; kx < 7; ++kx) {
                int xx = x + kx - 3;
                if (xx < 0 || xx > 31) continue;
                s += sp[yy * 32 + xx] * sw[ky * 7 + kx];
            }
        }
        oconv[(size_t)bc * 1024 + i] = s + bias;
    }
}

// ---------------------------------------------------------------------------
// LN + GELU + pw + tanh ONCE per pixel -> pos, then gather all 64 ch -> xs
// (f16). Unchanged from R19.
// ---------------------------------------------------------------------------
__global__ __launch_bounds__(256) void offset_sample_once_kernel(
    const float* __restrict__ oconv, const float* __restrict__ lng,
    const float* __restrict__ lnb, const float* __restrict__ pw,
    const float* __restrict__ x, float* __restrict__ pos,
    _Float16* __restrict__ xs)
{
    const int bg = blockIdx.y;
    const int px0 = blockIdx.x * 64;
    const int t = threadIdx.x;
    const int cg = t >> 6, pl = t & 63;
    const int px = px0 + pl;
    const int b = bg / 6, g = bg % 6;

    __shared__ float red[4][64];
    __shared__ float spos[64][2];

    const float* base = oconv + ((size_t)bg * 64 + cg * 16) * 1024 + px;
    float col[16];
    float s = 0.f;
#pragma unroll
    for (int i = 0; i < 16; ++i) { col[i] = base[(size_t)i * 1024]; s += col[i]; }
    red[cg][pl] = s;
    __syncthreads();
    float mu = (red[0][pl] + red[1][pl] + red[2][pl] + red[3][pl]) * (1.f / 64.f);
    float v = 0.f;
#pragma unroll
    for (int i = 0; i < 16; ++i) { float d = col[i] - mu; v += d * d; }
    __syncthreads();
    red[cg][pl] = v;
    __syncthreads();
    float inv = rsqrtf((red[0][pl] + red[1][pl] + red[2][pl] + red[3][pl]) * (1.f / 64.f) + 1e-5f);

    float oy = 0.f, ox = 0.f;
#pragma unroll
    for (int i = 0; i < 16; ++i) {
        int c = cg * 16 + i;
        float val = (col[i] - mu) * inv * lng[c] + lnb[c];
        float gl = 0.5f * val * (1.f + erff(val * 0.70710678118654752440f));
        oy += gl * pw[c];
        ox += gl * pw[64 + c];
    }
    __syncthreads();
    red[cg][pl] = oy;
    __syncthreads();
    float oyt = red[0][pl] + red[1][pl] + red[2][pl] + red[3][pl];
    __syncthreads();
    red[cg][pl] = ox;
    __syncthreads();
    if (cg == 0) {
        float oxt = red[0][pl] + red[1][pl] + red[2][pl] + red[3][pl];
        float offy = tanhf(oyt) * (2.0f / 32.0f);
        float offx = tanhf(oxt) * (2.0f / 32.0f);
        int y = px >> 5, xx = px & 31;
        float ry = ((y + 0.5f) / 32.f) * 2.f - 1.f;
        float rx = ((xx + 0.5f) / 32.f) * 2.f - 1.f;
        float pyv = offy + ry, pxv = offx + rx;
        spos[pl][0] = pyv; spos[pl][1] = pxv;
        pos[((size_t)bg * 1024 + px) * 2 + 0] = pyv;
        pos[((size_t)bg * 1024 + px) * 2 + 1] = pxv;
    }
    __syncthreads();

    float py = spos[pl][0], pxv = spos[pl][1];
    float gx = (pxv + 1.f) * 0.5f * 31.f;
    float gy = (py + 1.f) * 0.5f * 31.f;
    float x0f = floorf(gx), y0f = floorf(gy);
    float wx = gx - x0f, wy = gy - y0f;
    int x0 = (int)x0f, y0 = (int)y0f;
    float vx0 = ((unsigned)x0 <= 31u) ? 1.f : 0.f;
    float vx1 = ((unsigned)(x0 + 1) <= 31u) ? 1.f : 0.f;
    float vy0 = ((unsigned)y0 <= 31u) ? 1.f : 0.f;
    float vy1 = ((unsigned)(y0 + 1) <= 31u) ? 1.f : 0.f;
    float w00 = (1.f - wx) * (1.f - wy) * vx0 * vy0;
    float w01 = wx * (1.f - wy) * vx1 * vy0;
    float w10 = (1.f - wx) * wy * vx0 * vy1;
    float w11 = wx * wy * vx1 * vy1;
    int xc0 = min(max(x0, 0), 31), xc1 = min(max(x0 + 1, 0), 31);
    int yc0 = min(max(y0, 0), 31), yc1 = min(max(y0 + 1, 0), 31);
    int i00 = yc0 * 32 + xc0, i01 = yc0 * 32 + xc1;
    int i10 = yc1 * 32 + xc0, i11 = yc1 * 32 + xc1;

    const float* xg = x + ((size_t)b * CC + g * 64) * 1024;
    _Float16* xso = xs + ((size_t)b * CC + g * 64) * 1024 + px;
#pragma unroll
    for (int cs = 0; cs < 4; ++cs) {
        int c0 = cs * 16 + cg * 4;
#pragma unroll
        for (int i = 0; i < 4; ++i) {
            const float* plane = xg + (size_t)(c0 + i) * 1024;
            xso[(size_t)(c0 + i) * 1024] =
                (_Float16)(plane[i00] * w00 + plane[i01] * w01
                         + plane[i10] * w10 + plane[i11] * w11);
        }
    }
}

// ---------------------------------------------------------------------------
// MFMA flash attention, TWO HEADS PER BLOCK (unchanged from R16).
// ---------------------------------------------------------------------------
__global__ __launch_bounds__(256) void attn_mfma_kernel(
    const float* __restrict__ q, const _Float16* __restrict__ khT,
    const _Float16* __restrict__ vhb, const float* __restrict__ pos,
    const float* __restrict__ rpe, float* __restrict__ out)
{
    const int bgp = blockIdx.y;            // 0..11 = (b, g)
    const int b = bgp / 6, g = bgp % 6;
    const int h0 = g * 2;
    const int bh0 = b * 12 + h0, bh1 = bh0 + 1;
    const int mblk = blockIdx.x * 16;
    const int tid = threadIdx.x;
    const int w = tid >> 6, lane = tid & 63;
    const int quad = lane >> 4, lcol = lane & 15;

    __shared__ __align__(16) char smem[50944];
    half2_t*  srpeA = (half2_t*)smem;
    half2_t*  srpeB = (half2_t*)(smem + 8832);
    _Float16* sqh   = (_Float16*)(smem + 17664);
    _Float16* spw   = (_Float16*)(smem + 19712) + w * 2304;   // h0: +0, h1: +1152
    float*    cml0  = (float*)(smem + 38144);
    float*    cml1  = (float*)(smem + 38400);
    float2*   skxy  = (float2*)(smem + 38656);   // per-key {pos.x(=px), wy}
    int*      siy   = (int*)(smem + 46848);      // per-key ((int)y0f - r0)*63
    float*    comb0 = (float*)(smem + 19712);
    float*    comb1 = (float*)(smem + 19712 + 9216);

    const float qyw = (((mblk >> 5) + 0.5f) * (1.f / 32.f)) * 2.f - 1.f;
    int r0; {
        float gy_lo = (qyw - 1.03125f) * 15.5f + 31.f;
        r0 = (int)floorf(gy_lo);
        r0 = min(max(r0, 0), 28);
    }

    {   // stage both heads' RPE windows as head-interleaved half2 pair tables
        const float* rp0 = rpe + (size_t)h0 * 3969;
        const float* rp1 = rp0 + 3969;
        for (int i = tid; i < 35 * 63; i += 256) {
            int y = i / 63, xx = i - y * 63;
            int gi = (r0 + y) * 63 + xx;
            float a0 = rp0[gi], b0 = (xx < 62) ? rp0[gi + 1] : 0.f;
            float a1 = rp1[gi], b1 = (xx < 62) ? rp1[gi + 1] : 0.f;
            half2_t hA; hA[0] = (_Float16)a0; hA[1] = (_Float16)a1;   // {h0,h1} @ x
            half2_t hB; hB[0] = (_Float16)b0; hB[1] = (_Float16)b1;   // {h0,h1} @ x+1
            srpeA[i] = hA;
            srpeB[i] = hB;
        }
    }
    {   // stage q for both heads: [head][m][hc]
        const float* qb = q + ((size_t)b * CC + h0 * 32) * 1024 + mblk;
        for (int i = tid; i < 1024; i += 256) {
            int hh = i >> 9, rem = i & 511;
            int hc = rem >> 4, m = rem & 15;
            sqh[hh * 512 + m * 32 + hc] =
                (_Float16)qb[(size_t)(hh * 32 + hc) * 1024 + m];
        }
    }
    {   // stage per-key geometry: y-part is block-uniform per key
        const float2* pgv = (const float2*)(pos + (size_t)bgp * 2048);
        for (int i = tid; i < 1024; i += 256) {
            float2 pp = pgv[i];
            float gy = (qyw - pp.x) * 15.5f + 31.f;
            float y0f = floorf(gy);
            skxy[i] = make_float2(pp.y, gy - y0f);
            siy[i] = ((int)y0f - r0) * 63;
        }
    }
    __syncthreads();

    half8_t qf0 = *(const half8_t*)&sqh[lcol * 32 + quad * 8];
    half8_t qf1 = *(const half8_t*)&sqh[512 + lcol * 32 + quad * 8];
    const float qx = (((mblk & 31) + lcol + 0.5f) * (1.f / 32.f)) * 2.f - 1.f;

    const _Float16* khb0 = khT + (size_t)bh0 * 1024 * 32;
    const _Float16* khb1 = khT + (size_t)bh1 * 1024 * 32;
    const _Float16* vhh0 = vhb + (size_t)bh0 * 32 * 1024;
    const _Float16* vhh1 = vhb + (size_t)bh1 * 32 * 1024;

    f4_t o00 = {0.f, 0.f, 0.f, 0.f}, o01 = {0.f, 0.f, 0.f, 0.f};
    f4_t o10 = {0.f, 0.f, 0.f, 0.f}, o11 = {0.f, 0.f, 0.f, 0.f};
    float lsum0 = 0.f, lsum1 = 0.f;

#pragma unroll 1
    for (int c = 0; c < 4; ++c) {
        const int n0 = w * 256 + c * 64;

        // prefetch K fragments for both heads
        half8_t khv0[4], khv1[4];
#pragma unroll
        for (int t = 0; t < 4; ++t) {
            size_t off = (size_t)(n0 + t * 16 + lcol) * 32 + quad * 8;
            khv0[t] = *(const half8_t*)&khb0[off];
            khv1[t] = *(const half8_t*)&khb1[off];
        }

        f4_t S0[4], S1[4];
#pragma unroll
        for (int t = 0; t < 4; ++t) {
            f4_t s0 = {0.f, 0.f, 0.f, 0.f}, s1 = {0.f, 0.f, 0.f, 0.f};
            s0 = __builtin_amdgcn_mfma_f32_16x16x32_f16(khv0[t], qf0, s0, 0, 0, 0);
            s1 = __builtin_amdgcn_mfma_f32_16x16x32_f16(khv1[t], qf1, s1, 0, 0, 0);
#pragma unroll
            for (int r = 0; r < 4; ++r) {
                int key = n0 + t * 16 + quad * 4 + r;
                float2 kxy = skxy[key];          // LDS broadcast {px, wy}
                int iy = siy[key];               // LDS broadcast row offset
                float gx = (qx - kxy.x) * 15.5f + 31.f;
                float x0f = floorf(gx);
                float wxf = gx - x0f;
                int i00 = iy + (int)x0f;
                half2_t a0 = srpeA[i00];         // {h0,h1} @ (y0 , x0 )
                half2_t b0 = srpeB[i00];         // {h0,h1} @ (y0 , x0+1)
                half2_t a1 = srpeA[i00 + 63];    // {h0,h1} @ (y0+1, x0 )
                half2_t b1 = srpeB[i00 + 63];    // {h0,h1} @ (y0+1, x0+1)
                _Float16 wxs = (_Float16)wxf;
                _Float16 wys = (_Float16)kxy.y;
                half2_t wxh; wxh[0] = wxs; wxh[1] = wxs;
                half2_t wyh; wyh[0] = wys; wyh[1] = wys;
                half2_t top = a0 + (b0 - a0) * wxh;   // packed x-lerp, both heads
                half2_t bot = a1 + (b1 - a1) * wxh;
                half2_t res = top + (bot - top) * wyh; // packed y-lerp
                s0[r] = s0[r] * ATTN_SCALE + (float)res[0];
                s1[r] = s1[r] * ATTN_SCALE + (float)res[1];
            }
            S0[t] = s0; S1[t] = s1;
        }

        // prefetch V for head0 (covers exp-section latency)
        half8_t vv00[2], vv01[2];
#pragma unroll
        for (int kp = 0; kp < 2; ++kp) {
            int nb = n0 + kp * 32 + quad * 8;
            vv00[kp] = *(const half8_t*)&vhh0[(size_t)lcol * 1024 + nb];
            vv01[kp] = *(const half8_t*)&vhh0[(size_t)(16 + lcol) * 1024 + nb];
        }

        // fixed-shift exp + P stores for both heads
#pragma unroll
        for (int t = 0; t < 4; ++t) {
            float p0 = __expf(S0[t][0]), p1 = __expf(S0[t][1]);
            float p2 = __expf(S0[t][2]), p3 = __expf(S0[t][3]);
            lsum0 += (p0 + p1) + (p2 + p3);
            half4_t h;
            h[0] = (_Float16)p0; h[1] = (_Float16)p1;
            h[2] = (_Float16)p2; h[3] = (_Float16)p3;
            *(half4_t*)&spw[lcol * 72 + t * 16 + quad * 4] = h;
            float r0e = __expf(S1[t][0]), r1e = __expf(S1[t][1]);
            float r2e = __expf(S1[t][2]), r3e = __expf(S1[t][3]);
            lsum1 += (r0e + r1e) + (r2e + r3e);
            half4_t h1;
            h1[0] = (_Float16)r0e; h1[1] = (_Float16)r1e;
            h1[2] = (_Float16)r2e; h1[3] = (_Float16)r3e;
            *(half4_t*)&spw[1152 + lcol * 72 + t * 16 + quad * 4] = h1;
        }

        // PV head0 (wave-internal LDS read-back; no barrier)
#pragma unroll
        for (int kp = 0; kp < 2; ++kp) {
            half8_t pb = *(const half8_t*)&spw[lcol * 72 + kp * 32 + quad * 8];
            o00 = __builtin_amdgcn_mfma_f32_16x16x32_f16(vv00[kp], pb, o00, 0, 0, 0);
            o01 = __builtin_amdgcn_mfma_f32_16x16x32_f16(vv01[kp], pb, o01, 0, 0, 0);
        }
        // PV head1 (V loaded JIT)
#pragma unroll
        for (int kp = 0; kp < 2; ++kp) {
            int nb = n0 + kp * 32 + quad * 8;
            half8_t v0 = *(const half8_t*)&vhh1[(size_t)lcol * 1024 + nb];
            half8_t v1 = *(const half8_t*)&vhh1[(size_t)(16 + lcol) * 1024 + nb];
            half8_t pb = *(const half8_t*)&spw[1152 + lcol * 72 + kp * 32 + quad * 8];
            o10 = __builtin_amdgcn_mfma_f32_16x16x32_f16(v0, pb, o10, 0, 0, 0);
            o11 = __builtin_amdgcn_mfma_f32_16x16x32_f16(v1, pb, o11, 0, 0, 0);
        }
    }

    lsum0 += __shfl_xor(lsum0, 16); lsum0 += __shfl_xor(lsum0, 32);
    lsum1 += __shfl_xor(lsum1, 16); lsum1 += __shfl_xor(lsum1, 32);

    __syncthreads();   // all waves done with P slabs -> alias as comb0/comb1

    *(f4_t*)&comb0[(w * 16 + lcol) * 36 + quad * 4]      = o00;
    *(f4_t*)&comb0[(w * 16 + lcol) * 36 + 16 + quad * 4] = o01;
    *(f4_t*)&comb1[(w * 16 + lcol) * 36 + quad * 4]      = o10;
    *(f4_t*)&comb1[(w * 16 + lcol) * 36 + 16 + quad * 4] = o11;
    if (quad == 0) {
        cml0[w * 16 + lcol] = lsum0;
        cml1[w * 16 + lcol] = lsum1;
    }
    __syncthreads();

#pragma unroll
    for (int i = 0; i < 2; ++i) {
        int idx = tid + i * 256;
        int qq = idx >> 5, hc = idx & 31;
        {
            float L = cml0[qq] + cml0[16 + qq] + cml0[32 + qq] + cml0[48 + qq];
            float o = comb0[(0 * 16 + qq) * 36 + hc]
                    + comb0[(1 * 16 + qq) * 36 + hc]
                    + comb0[(2 * 16 + qq) * 36 + hc]
                    + comb0[(3 * 16 + qq) * 36 + hc];
            out[((size_t)b * CC + h0 * 32 + hc) * 1024 + mblk + qq] = o / L;
        }
        {
            float L = cml1[qq] + cml1[16 + qq] + cml1[32 + qq] + cml1[48 + qq];
            float o = comb1[(0 * 16 + qq) * 36 + hc]
                    + comb1[(1 * 16 + qq) * 36 + hc]
                    + comb1[(2 * 16 + qq) * 36 + hc]
                    + comb1[(3 * 16 + qq) * 36 + hc];
            out[((size_t)b * CC + (h0 + 1) * 32 + hc) * 1024 + mblk + qq] = o / L;
        }
    }
}

// ---------------------------------------------------------------------------
extern "C" void kernel_launch(void* const* d_in, const int* in_sizes, int n_in,
                              void* d_out, int out_size, void* d_ws, size_t ws_size,
                              hipStream_t stream) {
    const float* x   = (const float*)d_in[0];
    const float* Wq  = (const float*)d_in[1];
    const float* bq  = (const float*)d_in[2];
    const float* Wk  = (const float*)d_in[3];
    const float* bk  = (const float*)d_in[4];
    const float* Wv  = (const float*)d_in[5];
    const float* bv  = (const float*)d_in[6];
    const float* Wo  = (const float*)d_in[7];
    const float* bo  = (const float*)d_in[8];
    const float* dww = (const float*)d_in[9];
    const float* dwb = (const float*)d_in[10];
    const float* lng = (const float*)d_in[11];
    const float* lnb = (const float*)d_in[12];
    const float* pw  = (const float*)d_in[13];
    const float* rpe = (const float*)d_in[14];

    float* ws = (float*)d_ws;
    const size_t SZ = 786432;           // 2*384*1024 floats
    float* qbuf  = ws;
    _Float16* xs = (_Float16*)(ws + 1 * SZ);     // f16
    float* abuf  = ws + 2 * SZ;
    float* oconv = ws + 3 * SZ;
    _Float16* khT = (_Float16*)(ws + 4 * SZ);
    _Float16* vhb = (_Float16*)(ws + 5 * SZ);
    float* pos   = ws + 6 * SZ;

    dim3 gqo(32, 12, 2);                // R21: 32x32 tiles, 768 blocks
    gemm_wx<0><<<gqo, 256, 0, stream>>>(Wq, bq, x, qbuf);
    dwconv_kernel<<<768, 256, 0, stream>>>(qbuf, dww, dwb, oconv);
    offset_sample_once_kernel<<<dim3(16, 12), 256, 0, stream>>>(
        oconv, lng, lnb, pw, x, pos, xs);
    gemm_kv_fused<<<dim3(32, 12, 2), 256, 0, stream>>>(Wk, bk, Wv, bv, xs, khT, vhb);
    attn_mfma_kernel<<<dim3(64, 12), 256, 0, stream>>>(qbuf, khT, vhb, pos, rpe, abuf);
    gemm_wx<1><<<gqo, 256, 0, stream>>>(Wo, bo, abuf, (float*)d_out);
}

// Round 7
// 158.236 us; speedup vs baseline: 3.7538x; 1.0007x over previous
//
#include <hip/hip_runtime.h>
#include <hip/hip_fp16.h>
#include <math.h>

#define HH 32
#define WW 32
#define HWSZ 1024      // H*W
#define CC 384
#define NHEAD 12
#define NGROUP 6
#define HC 32
#define GC 64
#define NS 1024        // n_sample
#define ATTN_SCALE 0.17677669529663687f  // 32^-0.5

typedef _Float16 half8_t __attribute__((ext_vector_type(8)));
typedef _Float16 half4_t __attribute__((ext_vector_type(4)));
typedef _Float16 half2_t __attribute__((ext_vector_type(2)));
typedef float    f4_t    __attribute__((ext_vector_type(4)));

// ---------------------------------------------------------------------------
// R21 MFMA GEMM: Y = W·X + b. 32m x 32n tile, BK=32, grid (32,12,2)=768
// blocks -> 3 blocks/CU. Register prefetch of next K-tile between barriers.
// W pure f16; X pure f16 (XLO=0, q-proj) or f16 hi/lo (XLO=1, o-proj).
// ---------------------------------------------------------------------------
template<int XLO>
__global__ __launch_bounds__(256) void gemm_wx(
    const float* __restrict__ W, const float* __restrict__ bias,
    const float* __restrict__ X, float* __restrict__ Y)
{
    const int bz = blockIdx.z;
    const int tm = blockIdx.y * 32;
    const int tn = blockIdx.x * 32;
    const int tid = threadIdx.x;
    const int w = tid >> 6, lane = tid & 63;
    const int quad = lane >> 4, lcol = lane & 15;
    const int wr = w >> 1, wc = w & 1;       // wave's output quadrant

    __shared__ _Float16 sW[32][40];
    __shared__ _Float16 sX[32][40];
    __shared__ _Float16 sXl[XLO ? 32 : 1][40];

    const float* Xb = X + (size_t)bz * CC * 1024;
    float* Yb = Y + (size_t)bz * CC * 1024;

    const int m  = tid >> 3;
    const int j4 = (tid & 7) * 4;

    float4 wv = *(const float4*)&W[(size_t)(tm + m) * CC + j4];
    float4 xv = *(const float4*)&Xb[(size_t)m * 1024 + tn + j4];

    f4_t acc = {0.f, 0.f, 0.f, 0.f};

#pragma unroll 1
    for (int k0 = 0; k0 < CC; k0 += 32) {
        {
            half4_t hw; hw[0] = (_Float16)wv.x; hw[1] = (_Float16)wv.y;
            hw[2] = (_Float16)wv.z; hw[3] = (_Float16)wv.w;
            *(half4_t*)&sW[m][j4] = hw;
#pragma unroll
            for (int i = 0; i < 4; ++i) {
                float v = (i == 0) ? xv.x : (i == 1) ? xv.y : (i == 2) ? xv.z : xv.w;
                _Float16 h = (_Float16)v;
                sX[j4 + i][m] = h;
                if (XLO) sXl[j4 + i][m] = (_Float16)(v - (float)h);
            }
        }
        __syncthreads();

        if (k0 + 32 < CC) {
            wv = *(const float4*)&W[(size_t)(tm + m) * CC + k0 + 32 + j4];
            xv = *(const float4*)&Xb[(size_t)(k0 + 32 + m) * 1024 + tn + j4];
        }

        half8_t A = *(const half8_t*)&sW[wr * 16 + lcol][quad * 8];
        half8_t B = *(const half8_t*)&sX[wc * 16 + lcol][quad * 8];
        acc = __builtin_amdgcn_mfma_f32_16x16x32_f16(A, B, acc, 0, 0, 0);
        if (XLO) {
            half8_t Bl = *(const half8_t*)&sXl[wc * 16 + lcol][quad * 8];
            acc = __builtin_amdgcn_mfma_f32_16x16x32_f16(A, Bl, acc, 0, 0, 0);
        }
        __syncthreads();
    }

#pragma unroll
    for (int r = 0; r < 4; ++r) {
        int m0 = tm + wr * 16 + quad * 4 + r;
        Yb[(size_t)m0 * 1024 + tn + wc * 16 + lcol] = acc[r] + bias[m0];
    }
}

// ---------------------------------------------------------------------------
// R21 FUSED MFMA K+V projection, 32n tiles, grid (32,12,2)=768 blocks.
// ---------------------------------------------------------------------------
__global__ __launch_bounds__(256) void gemm_kv_fused(
    const float* __restrict__ Wk, const float* __restrict__ bk,
    const float* __restrict__ Wv, const float* __restrict__ bv,
    const _Float16* __restrict__ X,
    _Float16* __restrict__ khT, _Float16* __restrict__ vhb)
{
    const int bz = blockIdx.z;
    const int head = blockIdx.y;
    const int tm = head * 32;
    const int tn = blockIdx.x * 32;
    const int tid = threadIdx.x;
    const int w = tid >> 6, lane = tid & 63;
    const int quad = lane >> 4, lcol = lane & 15;
    const int bh = bz * 12 + head;
    const int nt = w & 1;

    __shared__ _Float16 sWk[32][40], sWv[32][40];
    __shared__ _Float16 sX[32][40];

    const _Float16* Xb = X + (size_t)bz * CC * 1024;

    const int m  = tid >> 3;
    const int j4 = (tid & 7) * 4;

    float4 wkv = *(const float4*)&Wk[(size_t)(tm + m) * CC + j4];
    float4 wvv = *(const float4*)&Wv[(size_t)(tm + m) * CC + j4];
    half4_t xh = *(const half4_t*)&Xb[(size_t)m * 1024 + tn + j4];

    f4_t a0 = {0.f, 0.f, 0.f, 0.f}, a1 = {0.f, 0.f, 0.f, 0.f};

#pragma unroll 1
    for (int k0 = 0; k0 < CC; k0 += 32) {
        {
            half4_t hk; hk[0] = (_Float16)wkv.x; hk[1] = (_Float16)wkv.y;
            hk[2] = (_Float16)wkv.z; hk[3] = (_Float16)wkv.w;
            half4_t hv; hv[0] = (_Float16)wvv.x; hv[1] = (_Float16)wvv.y;
            hv[2] = (_Float16)wvv.z; hv[3] = (_Float16)wvv.w;
            *(half4_t*)&sWk[m][j4] = hk;
            *(half4_t*)&sWv[m][j4] = hv;
#pragma unroll
            for (int i = 0; i < 4; ++i)
                sX[j4 + i][m] = xh[i];
        }
        __syncthreads();

        if (k0 + 32 < CC) {
            wkv = *(const float4*)&Wk[(size_t)(tm + m) * CC + k0 + 32 + j4];
            wvv = *(const float4*)&Wv[(size_t)(tm + m) * CC + k0 + 32 + j4];
            xh  = *(const half4_t*)&Xb[(size_t)(k0 + 32 + m) * 1024 + tn + j4];
        }

        half8_t Xa = *(const half8_t*)&sX[nt * 16 + lcol][quad * 8];
        if (w < 2) {
            half8_t K0 = *(const half8_t*)&sWk[lcol][quad * 8];
            half8_t K1 = *(const half8_t*)&sWk[16 + lcol][quad * 8];
            a0 = __builtin_amdgcn_mfma_f32_16x16x32_f16(Xa, K0, a0, 0, 0, 0);
            a1 = __builtin_amdgcn_mfma_f32_16x16x32_f16(Xa, K1, a1, 0, 0, 0);
        } else {
            half8_t V0 = *(const half8_t*)&sWv[lcol][quad * 8];
            half8_t V1 = *(const half8_t*)&sWv[16 + lcol][quad * 8];
            a0 = __builtin_amdgcn_mfma_f32_16x16x32_f16(V0, Xa, a0, 0, 0, 0);
            a1 = __builtin_amdgcn_mfma_f32_16x16x32_f16(V1, Xa, a1, 0, 0, 0);
        }
        __syncthreads();
    }

    if (w < 2) {
        float bk0 = bk[tm + lcol], bk1 = bk[tm + 16 + lcol];
#pragma unroll
        for (int r = 0; r < 4; ++r) {
            int n = tn + nt * 16 + quad * 4 + r;
            khT[((size_t)bh * 1024 + n) * 32 + lcol]      = (_Float16)(a0[r] + bk0);
            khT[((size_t)bh * 1024 + n) * 32 + 16 + lcol] = (_Float16)(a1[r] + bk1);
        }
    } else {
#pragma unroll
        for (int r = 0; r < 4; ++r) {
            int hc0 = quad * 4 + r;
            vhb[((size_t)bh * 32 + hc0) * 1024 + tn + nt * 16 + lcol] =
                (_Float16)(a0[r] + bv[tm + hc0]);
            vhb[((size_t)bh * 32 + hc0 + 16) * 1024 + tn + nt * 16 + lcol] =
                (_Float16)(a1[r] + bv[tm + hc0 + 16]);
        }
    }
}

// ---------------------------------------------------------------------------
// Depthwise 7x7 conv, zero pad 3 (unchanged).
// ---------------------------------------------------------------------------
__global__ __launch_bounds__(256) void dwconv_kernel(
    const float* __restrict__ q, const float* __restrict__ dww,
    const float* __restrict__ dwb, float* __restrict__ oconv)
{
    const int bc = blockIdx.x;
    const int bg = bc >> 6, c = bc & 63;
    const int b = bg / 6, g = bg % 6;
    const float* plane = q + ((size_t)b * CC + g * 64 + c) * 1024;

    __shared__ float sp[1024];
    __shared__ float sw[49];
    const int tid = threadIdx.x;
    for (int i = tid; i < 1024; i += 256) sp[i] = plane[i];
    if (tid < 49) sw[tid] = dww[c * 49 + tid];
    __syncthreads();

    const float bias = dwb[c];
    for (int i = tid; i < 1024; i += 256) {
        int y = i >> 5, x = i & 31;
        float s = 0.f;
#pragma unroll
        for (int ky = 0; ky < 7; ++ky) {
            int yy = y + ky - 3;
            if (yy < 0 || yy > 31) continue;
#pragma unroll
            for (int kx = 0; kx < 7; ++kx) {
                int xx = x + kx - 3;
                if (xx < 0 || xx > 31) continue;
                s += sp[yy * 32 + xx] * sw[ky * 7 + kx];
            }
        }
        oconv[(size_t)bc * 1024 + i] = s + bias;
    }
}

// ---------------------------------------------------------------------------
// R22: LN + GELU + pw + tanh once per pixel -> pos, then gather all 64 ch
// -> xs (f16). REGRIDDED: 32 px x 8 ch-groups per block, grid (32,12)=384
// blocks (was 192 = 0.75/CU, grid-starved per R20 calibration).
// ---------------------------------------------------------------------------
__global__ __launch_bounds__(256) void offset_sample_once_kernel(
    const float* __restrict__ oconv, const float* __restrict__ lng,
    const float* __restrict__ lnb, const float* __restrict__ pw,
    const float* __restrict__ x, float* __restrict__ pos,
    _Float16* __restrict__ xs)
{
    const int bg = blockIdx.y;
    const int px0 = blockIdx.x * 32;
    const int t = threadIdx.x;
    const int cg = t >> 5;          // 0..7 channel group (8 ch each)
    const int pl = t & 31;          // 0..31 pixel
    const int px = px0 + pl;
    const int b = bg / 6, g = bg % 6;

    __shared__ float red[8][32];
    __shared__ float spos[32][2];

    const float* base = oconv + ((size_t)bg * 64 + cg * 8) * 1024 + px;
    float col[8];
    float s = 0.f;
#pragma unroll
    for (int i = 0; i < 8; ++i) { col[i] = base[(size_t)i * 1024]; s += col[i]; }
    red[cg][pl] = s;
    __syncthreads();
    float mu = 0.f;
#pragma unroll
    for (int j = 0; j < 8; ++j) mu += red[j][pl];
    mu *= (1.f / 64.f);
    float v = 0.f;
#pragma unroll
    for (int i = 0; i < 8; ++i) { float d = col[i] - mu; v += d * d; }
    __syncthreads();
    red[cg][pl] = v;
    __syncthreads();
    float vs = 0.f;
#pragma unroll
    for (int j = 0; j < 8; ++j) vs += red[j][pl];
    float inv = rsqrtf(vs * (1.f / 64.f) + 1e-5f);

    float oy = 0.f, ox = 0.f;
#pragma unroll
    for (int i = 0; i < 8; ++i) {
        int c = cg * 8 + i;
        float val = (col[i] - mu) * inv * lng[c] + lnb[c];
        float gl = 0.5f * val * (1.f + erff(val * 0.70710678118654752440f));
        oy += gl * pw[c];
        ox += gl * pw[64 + c];
    }
    __syncthreads();
    red[cg][pl] = oy;
    __syncthreads();
    float oyt = 0.f;
#pragma unroll
    for (int j = 0; j < 8; ++j) oyt += red[j][pl];
    __syncthreads();
    red[cg][pl] = ox;
    __syncthreads();
    if (cg == 0) {
        float oxt = 0.f;
#pragma unroll
        for (int j = 0; j < 8; ++j) oxt += red[j][pl];
        float offy = tanhf(oyt) * (2.0f / 32.0f);
        float offx = tanhf(oxt) * (2.0f / 32.0f);
        int y = px >> 5, xx = px & 31;
        float ry = ((y + 0.5f) / 32.f) * 2.f - 1.f;
        float rx = ((xx + 0.5f) / 32.f) * 2.f - 1.f;
        float pyv = offy + ry, pxv = offx + rx;
        spos[pl][0] = pyv; spos[pl][1] = pxv;
        pos[((size_t)bg * 1024 + px) * 2 + 0] = pyv;
        pos[((size_t)bg * 1024 + px) * 2 + 1] = pxv;
    }
    __syncthreads();

    float py = spos[pl][0], pxv = spos[pl][1];
    float gx = (pxv + 1.f) * 0.5f * 31.f;
    float gy = (py + 1.f) * 0.5f * 31.f;
    float x0f = floorf(gx), y0f = floorf(gy);
    float wx = gx - x0f, wy = gy - y0f;
    int x0 = (int)x0f, y0 = (int)y0f;
    float vx0 = ((unsigned)x0 <= 31u) ? 1.f : 0.f;
    float vx1 = ((unsigned)(x0 + 1) <= 31u) ? 1.f : 0.f;
    float vy0 = ((unsigned)y0 <= 31u) ? 1.f : 0.f;
    float vy1 = ((unsigned)(y0 + 1) <= 31u) ? 1.f : 0.f;
    float w00 = (1.f - wx) * (1.f - wy) * vx0 * vy0;
    float w01 = wx * (1.f - wy) * vx1 * vy0;
    float w10 = (1.f - wx) * wy * vx0 * vy1;
    float w11 = wx * wy * vx1 * vy1;
    int xc0 = min(max(x0, 0), 31), xc1 = min(max(x0 + 1, 0), 31);
    int yc0 = min(max(y0, 0), 31), yc1 = min(max(y0 + 1, 0), 31);
    int i00 = yc0 * 32 + xc0, i01 = yc0 * 32 + xc1;
    int i10 = yc1 * 32 + xc0, i11 = yc1 * 32 + xc1;

    const float* xg = x + ((size_t)b * CC + g * 64) * 1024;
    _Float16* xso = xs + ((size_t)b * CC + g * 64) * 1024 + px;
#pragma unroll
    for (int i = 0; i < 8; ++i) {
        int c = cg * 8 + i;
        const float* plane = xg + (size_t)c * 1024;
        xso[(size_t)c * 1024] =
            (_Float16)(plane[i00] * w00 + plane[i01] * w01
                     + plane[i10] * w10 + plane[i11] * w11);
    }
}

// ---------------------------------------------------------------------------
// MFMA flash attention, TWO HEADS PER BLOCK. R22 changes:
//  (a) srpeB table removed — provably srpeB[i] == srpeA[i+1] for all used
//      indices (x0f <= 61), so taps read A[i00]/A[i00+1]/A[i00+63]/A[i00+64].
//      Halves RPE staging; LDS 50944 -> 42112.
//  (b) per-key u = 31 - px*15.5 precomputed -> gx = qxs + u (1 VALU).
//  (c) ATTN_SCALE folded into q staging (drops 2 VALU per (t,r)).
//  (d) K fragments double-buffered across c-iterations (named reg sets,
//      unroll-by-2) — L2 latency hides under previous iteration compute.
// ---------------------------------------------------------------------------
__global__ __launch_bounds__(256) void attn_mfma_kernel(
    const float* __restrict__ q, const _Float16* __restrict__ khT,
    const _Float16* __restrict__ vhb, const float* __restrict__ pos,
    const float* __restrict__ rpe, float* __restrict__ out)
{
    const int bgp = blockIdx.y;            // 0..11 = (b, g)
    const int b = bgp / 6, g = bgp % 6;
    const int h0 = g * 2;
    const int bh0 = b * 12 + h0, bh1 = bh0 + 1;
    const int mblk = blockIdx.x * 16;
    const int tid = threadIdx.x;
    const int w = tid >> 6, lane = tid & 63;
    const int quad = lane >> 4, lcol = lane & 15;

    __shared__ __align__(16) char smem[42112];
    half2_t*  srpeA = (half2_t*)smem;                        // 2205 x {h0,h1}
    _Float16* sqh   = (_Float16*)(smem + 8832);              // 2048B
    _Float16* spw   = (_Float16*)(smem + 10880) + w * 2304;  // P slabs
    float*    comb0 = (float*)(smem + 10880);                // alias P slabs
    float*    comb1 = (float*)(smem + 20096);
    float*    cml0  = (float*)(smem + 29312);
    float*    cml1  = (float*)(smem + 29568);
    float2*   skxy  = (float2*)(smem + 29824);               // {u, wy} per key
    int*      siy   = (int*)(smem + 38016);                  // row offset per key

    const float qyw = (((mblk >> 5) + 0.5f) * (1.f / 32.f)) * 2.f - 1.f;
    int r0; {
        float gy_lo = (qyw - 1.03125f) * 15.5f + 31.f;
        r0 = (int)floorf(gy_lo);
        r0 = min(max(r0, 0), 28);
    }

    {   // stage both heads' RPE window, head-interleaved (single table)
        const float* rp0 = rpe + (size_t)h0 * 3969;
        const float* rp1 = rp0 + 3969;
        for (int i = tid; i < 35 * 63; i += 256) {
            int y = i / 63, xx = i - y * 63;
            int gi = (r0 + y) * 63 + xx;
            half2_t hA; hA[0] = (_Float16)rp0[gi]; hA[1] = (_Float16)rp1[gi];
            srpeA[i] = hA;
        }
    }
    {   // stage q (pre-scaled by ATTN_SCALE) for both heads: [head][m][hc]
        const float* qb = q + ((size_t)b * CC + h0 * 32) * 1024 + mblk;
        for (int i = tid; i < 1024; i += 256) {
            int hh = i >> 9, rem = i & 511;
            int hc = rem >> 4, m = rem & 15;
            sqh[hh * 512 + m * 32 + hc] =
                (_Float16)(qb[(size_t)(hh * 32 + hc) * 1024 + m] * ATTN_SCALE);
        }
    }
    {   // per-key geometry: u = 31 - px*15.5, wy, row offset
        const float2* pgv = (const float2*)(pos + (size_t)bgp * 2048);
        for (int i = tid; i < 1024; i += 256) {
            float2 pp = pgv[i];
            float gy = (qyw - pp.x) * 15.5f + 31.f;
            float y0f = floorf(gy);
            skxy[i] = make_float2(31.f - pp.y * 15.5f, gy - y0f);
            siy[i] = ((int)y0f - r0) * 63;
        }
    }
    __syncthreads();

    half8_t qf0 = *(const half8_t*)&sqh[lcol * 32 + quad * 8];
    half8_t qf1 = *(const half8_t*)&sqh[512 + lcol * 32 + quad * 8];
    const float qxs = ((mblk & 31) + lcol + 0.5f) * 0.96875f - 15.5f;  // qx*15.5

    const _Float16* khb0 = khT + (size_t)bh0 * 1024 * 32;
    const _Float16* khb1 = khT + (size_t)bh1 * 1024 * 32;
    const _Float16* vhh0 = vhb + (size_t)bh0 * 32 * 1024;
    const _Float16* vhh1 = vhb + (size_t)bh1 * 32 * 1024;

    f4_t o00 = {0.f, 0.f, 0.f, 0.f}, o01 = {0.f, 0.f, 0.f, 0.f};
    f4_t o10 = {0.f, 0.f, 0.f, 0.f}, o11 = {0.f, 0.f, 0.f, 0.f};
    float lsum0 = 0.f, lsum1 = 0.f;

    half8_t kA0[4], kA1[4], kB0[4], kB1[4];

    auto loadK = [&](half8_t* d0, half8_t* d1, int cc) {
        int nn = w * 256 + cc * 64;
#pragma unroll
        for (int t = 0; t < 4; ++t) {
            size_t off = (size_t)(nn + t * 16 + lcol) * 32 + quad * 8;
            d0[t] = *(const half8_t*)&khb0[off];
            d1[t] = *(const half8_t*)&khb1[off];
        }
    };

    auto computeC = [&](const half8_t* kh0, const half8_t* kh1, int c) {
        const int n0 = w * 256 + c * 64;

        f4_t S0[4], S1[4];
#pragma unroll
        for (int t = 0; t < 4; ++t) {
            f4_t s0 = {0.f, 0.f, 0.f, 0.f}, s1 = {0.f, 0.f, 0.f, 0.f};
            s0 = __builtin_amdgcn_mfma_f32_16x16x32_f16(kh0[t], qf0, s0, 0, 0, 0);
            s1 = __builtin_amdgcn_mfma_f32_16x16x32_f16(kh1[t], qf1, s1, 0, 0, 0);
#pragma unroll
            for (int r = 0; r < 4; ++r) {
                int key = n0 + t * 16 + quad * 4 + r;
                float2 kxy = skxy[key];          // {u, wy} broadcast
                int iy = siy[key];
                float gx = qxs + kxy.x;
                float x0f = floorf(gx);
                int i00 = iy + (int)x0f;
                half2_t a0 = srpeA[i00];
                half2_t b0 = srpeA[i00 + 1];
                half2_t a1 = srpeA[i00 + 63];
                half2_t b1 = srpeA[i00 + 64];
                _Float16 wxs = (_Float16)(gx - x0f);
                _Float16 wys = (_Float16)kxy.y;
                half2_t wxh; wxh[0] = wxs; wxh[1] = wxs;
                half2_t wyh; wyh[0] = wys; wyh[1] = wys;
                half2_t top = a0 + (b0 - a0) * wxh;
                half2_t bot = a1 + (b1 - a1) * wxh;
                half2_t res = top + (bot - top) * wyh;
                s0[r] = s0[r] + (float)res[0];    // scale pre-folded into q
                s1[r] = s1[r] + (float)res[1];
            }
            S0[t] = s0; S1[t] = s1;
        }

        // prefetch V for head0 (covers exp-section latency)
        half8_t vv00[2], vv01[2];
#pragma unroll
        for (int kp = 0; kp < 2; ++kp) {
            int nb = n0 + kp * 32 + quad * 8;
            vv00[kp] = *(const half8_t*)&vhh0[(size_t)lcol * 1024 + nb];
            vv01[kp] = *(const half8_t*)&vhh0[(size_t)(16 + lcol) * 1024 + nb];
        }

        // fixed-shift exp + P stores for both heads
#pragma unroll
        for (int t = 0; t < 4; ++t) {
            float p0 = __expf(S0[t][0]), p1 = __expf(S0[t][1]);
            float p2 = __expf(S0[t][2]), p3 = __expf(S0[t][3]);
            lsum0 += (p0 + p1) + (p2 + p3);
            half4_t h;
            h[0] = (_Float16)p0; h[1] = (_Float16)p1;
            h[2] = (_Float16)p2; h[3] = (_Float16)p3;
            *(half4_t*)&spw[lcol * 72 + t * 16 + quad * 4] = h;
            float r0e = __expf(S1[t][0]), r1e = __expf(S1[t][1]);
            float r2e = __expf(S1[t][2]), r3e = __expf(S1[t][3]);
            lsum1 += (r0e + r1e) + (r2e + r3e);
            half4_t h1;
            h1[0] = (_Float16)r0e; h1[1] = (_Float16)r1e;
            h1[2] = (_Float16)r2e; h1[3] = (_Float16)r3e;
            *(half4_t*)&spw[1152 + lcol * 72 + t * 16 + quad * 4] = h1;
        }

        // PV head0 (wave-internal LDS read-back; no barrier)
#pragma unroll
        for (int kp = 0; kp < 2; ++kp) {
            half8_t pb = *(const half8_t*)&spw[lcol * 72 + kp * 32 + quad * 8];
            o00 = __builtin_amdgcn_mfma_f32_16x16x32_f16(vv00[kp], pb, o00, 0, 0, 0);
            o01 = __builtin_amdgcn_mfma_f32_16x16x32_f16(vv01[kp], pb, o01, 0, 0, 0);
        }
        // PV head1 (V loaded JIT)
#pragma unroll
        for (int kp = 0; kp < 2; ++kp) {
            int nb = n0 + kp * 32 + quad * 8;
            half8_t v0 = *(const half8_t*)&vhh1[(size_t)lcol * 1024 + nb];
            half8_t v1 = *(const half8_t*)&vhh1[(size_t)(16 + lcol) * 1024 + nb];
            half8_t pb = *(const half8_t*)&spw[1152 + lcol * 72 + kp * 32 + quad * 8];
            o10 = __builtin_amdgcn_mfma_f32_16x16x32_f16(v0, pb, o10, 0, 0, 0);
            o11 = __builtin_amdgcn_mfma_f32_16x16x32_f16(v1, pb, o11, 0, 0, 0);
        }
    };

    loadK(kA0, kA1, 0);
#pragma unroll 1
    for (int it = 0; it < 2; ++it) {
        int c = it * 2;
        loadK(kB0, kB1, c + 1);          // prefetch c+1 before computing c
        computeC(kA0, kA1, c);
        if (it == 0) loadK(kA0, kA1, c + 2);
        computeC(kB0, kB1, c + 1);
    }

    lsum0 += __shfl_xor(lsum0, 16); lsum0 += __shfl_xor(lsum0, 32);
    lsum1 += __shfl_xor(lsum1, 16); lsum1 += __shfl_xor(lsum1, 32);

    __syncthreads();   // all waves done with P slabs -> alias as comb0/comb1

    *(f4_t*)&comb0[(w * 16 + lcol) * 36 + quad * 4]      = o00;
    *(f4_t*)&comb0[(w * 16 + lcol) * 36 + 16 + quad * 4] = o01;
    *(f4_t*)&comb1[(w * 16 + lcol) * 36 + quad * 4]      = o10;
    *(f4_t*)&comb1[(w * 16 + lcol) * 36 + 16 + quad * 4] = o11;
    if (quad == 0) {
        cml0[w * 16 + lcol] = lsum0;
        cml1[w * 16 + lcol] = lsum1;
    }
    __syncthreads();

#pragma unroll
    for (int i = 0; i < 2; ++i) {
        int idx = tid + i * 256;
        int qq = idx >> 5, hc = idx & 31;
        {
            float L = cml0[qq] + cml0[16 + qq] + cml0[32 + qq] + cml0[48 + qq];
            float o = comb0[(0 * 16 + qq) * 36 + hc]
                    + comb0[(1 * 16 + qq) * 36 + hc]
                    + comb0[(2 * 16 + qq) * 36 + hc]
                    + comb0[(3 * 16 + qq) * 36 + hc];
            out[((size_t)b * CC + h0 * 32 + hc) * 1024 + mblk + qq] = o / L;
        }
        {
            float L = cml1[qq] + cml1[16 + qq] + cml1[32 + qq] + cml1[48 + qq];
            float o = comb1[(0 * 16 + qq) * 36 + hc]
                    + comb1[(1 * 16 + qq) * 36 + hc]
                    + comb1[(2 * 16 + qq) * 36 + hc]
                    + comb1[(3 * 16 + qq) * 36 + hc];
            out[((size_t)b * CC + (h0 + 1) * 32 + hc) * 1024 + mblk + qq] = o / L;
        }
    }
}

// ---------------------------------------------------------------------------
extern "C" void kernel_launch(void* const* d_in, const int* in_sizes, int n_in,
                              void* d_out, int out_size, void* d_ws, size_t ws_size,
                              hipStream_t stream) {
    const float* x   = (const float*)d_in[0];
    const float* Wq  = (const float*)d_in[1];
    const float* bq  = (const float*)d_in[2];
    const float* Wk  = (const float*)d_in[3];
    const float* bk  = (const float*)d_in[4];
    const float* Wv  = (const float*)d_in[5];
    const float* bv  = (const float*)d_in[6];
    const float* Wo  = (const float*)d_in[7];
    const float* bo  = (const float*)d_in[8];
    const float* dww = (const float*)d_in[9];
    const float* dwb = (const float*)d_in[10];
    const float* lng = (const float*)d_in[11];
    const float* lnb = (const float*)d_in[12];
    const float* pw  = (const float*)d_in[13];
    const float* rpe = (const float*)d_in[14];

    float* ws = (float*)d_ws;
    const size_t SZ = 786432;           // 2*384*1024 floats
    float* qbuf  = ws;
    _Float16* xs = (_Float16*)(ws + 1 * SZ);     // f16
    float* abuf  = ws + 2 * SZ;
    float* oconv = ws + 3 * SZ;
    _Float16* khT = (_Float16*)(ws + 4 * SZ);
    _Float16* vhb = (_Float16*)(ws + 5 * SZ);
    float* pos   = ws + 6 * SZ;

    dim3 gqo(32, 12, 2);                // 32x32 tiles, 768 blocks
    gemm_wx<0><<<gqo, 256, 0, stream>>>(Wq, bq, x, qbuf);
    dwconv_kernel<<<768, 256, 0, stream>>>(qbuf, dww, dwb, oconv);
    offset_sample_once_kernel<<<dim3(32, 12), 256, 0, stream>>>(
        oconv, lng, lnb, pw, x, pos, xs);
    gemm_kv_fused<<<dim3(32, 12, 2), 256, 0, stream>>>(Wk, bk, Wv, bv, xs, khT, vhb);
    attn_mfma_kernel<<<dim3(64, 12), 256, 0, stream>>>(qbuf, khT, vhb, pos, rpe, abuf);
    gemm_wx<1><<<gqo, 256, 0, stream>>>(Wo, bo, abuf, (float*)d_out);
}